// Round 8
// baseline (305.406 us; speedup 1.0000x reference)
//
#include <hip/hip_runtime.h>
#include <hip/hip_bf16.h>

#define NN 100000
#define EE 1600000
#define BSZ 512    // dst-nodes per coarse bucket
#define NBKT 196   // ceil(NN/BSZ)
#define CHUNK 8192 // edges per coarse chunk
#define NCH 196    // ceil(EE/CHUNK)

// k_tobfW role ranges — single source of truth for BOTH the in-kernel dispatch
// and the launch grid. R6 crash: grid literal too large. R7 crash: HBLK0 was
// XBLK+2 while W-pack ran at b==XBLK, so block XBLK+1 computed ch=-1 and
// corrupted chunkhist row boundaries. Derivation now: x-convert [0,XBLK),
// W-pack {XBLK}, histograms [HBLK0, HBLK0+NCH) with HBLK0 = XBLK+1.
#define XBLK 3125              // x-convert blocks (512 float4 each)
#define HBLK0 (XBLK + 1)       // first histogram block (W-pack block is XBLK)
#define TOBFW_GRID (HBLK0 + NCH)

typedef short bf16x8 __attribute__((ext_vector_type(8)));
typedef float f32x4 __attribute__((ext_vector_type(4)));
typedef float f32x2 __attribute__((ext_vector_type(2)));

// ---------------- bf16 helpers ----------------
__device__ inline unsigned short bf16_of(float f) {
    __hip_bfloat16 h = __float2bfloat16(f);   // RNE
    return *reinterpret_cast<unsigned short*>(&h);
}
__device__ inline unsigned pack2(float a, float b) {
    return (unsigned)bf16_of(a) | ((unsigned)bf16_of(b) << 16);
}
__device__ inline float bflo(unsigned u) { return __uint_as_float(u << 16); }
__device__ inline float bfhi(unsigned u) { return __uint_as_float(u & 0xffff0000u); }
__device__ inline f32x2 unpk2(unsigned u) {
    f32x2 r; r.x = __uint_as_float(u << 16); r.y = __uint_as_float(u & 0xffff0000u);
    return r;
}

// BN finalize prologue (replaces k_bnfin): reduce bnacc[8][128] -> ls[0..63]=scale,
// ls[64..127]=shift. Same op order + division as the old k_bnfin -> identical
// values in every consumer block. ~1us aggregate L2 cost across all blocks.
#define BN_PROLOGUE(bnaccp, gp, bep, lsbuf) do {                               \
    if (threadIdx.x < 128) {                                                   \
        float a_ = 0.f;                                                        \
        _Pragma("unroll")                                                      \
        for (int r_ = 0; r_ < 8; ++r_) a_ += (bnaccp)[r_ * 128 + threadIdx.x]; \
        (lsbuf)[threadIdx.x] = a_;                                             \
    }                                                                          \
    __syncthreads();                                                           \
    if (threadIdx.x < 64) {                                                    \
        float mu_ = (lsbuf)[threadIdx.x] / (float)NN;                          \
        float var_ = (lsbuf)[64 + threadIdx.x] / (float)NN - mu_ * mu_;        \
        var_ = fmaxf(var_, 0.0f);                                              \
        float sc_ = (gp)[threadIdx.x] / sqrtf(var_ + 1e-5f);                   \
        (lsbuf)[threadIdx.x] = sc_;                                            \
        (lsbuf)[64 + threadIdx.x] = (bep)[threadIdx.x] - mu_ * sc_;            \
    }                                                                          \
    __syncthreads();                                                           \
} while (0)

// ---------------- fused: x->bf16 (32B/thread) + W packing + per-chunk dst hists ----
// Blocks [0,XBLK): x -> bf16, 512 float4 per block. Block XBLK: W pack + zero
// bnacc[2048]. Blocks [HBLK0, HBLK0+NCH): per-chunk histogram of dst buckets ->
// chunkhist[b*NCH+ch] (private row per block: no zero-init, no global atomics).
__global__ __launch_bounds__(256)
void k_tobfW(const float4* __restrict__ src, ushort4* __restrict__ dst,
             const float* __restrict__ Wl1, const float* __restrict__ Wr1,
             const float* __restrict__ Wl2, const float* __restrict__ Wr2,
             unsigned short* __restrict__ w1, unsigned short* __restrict__ w2,
             const int* __restrict__ ei, int* __restrict__ chunkhist,
             float* __restrict__ bnacc) {
    int b = blockIdx.x, tid = threadIdx.x;
    if (b < XBLK) {
        int i = b * 512 + tid;
        float4 v0 = src[i];
        float4 v1 = src[i + 256];
        dst[i]       = make_ushort4(bf16_of(v0.x), bf16_of(v0.y), bf16_of(v0.z), bf16_of(v0.w));
        dst[i + 256] = make_ushort4(bf16_of(v1.x), bf16_of(v1.y), bf16_of(v1.z), bf16_of(v1.w));
    } else if (b == XBLK) {
        for (int i = tid; i < 8192; i += 256) {
            int n = i >> 7, k = i & 127;
            float v1 = (k < 64) ? Wl1[n * 64 + k] : Wr1[n * 64 + (k - 64)];
            w1[i] = bf16_of(v1);
            float v2 = (k < 64) ? Wl2[n * 64 + k] : Wr2[n * 64 + (k - 64)];
            w2[i] = bf16_of(v2);
        }
        for (int i = tid; i < 2048; i += 256) bnacc[i] = 0.f;
    } else {
        __shared__ int hist[NBKT];
        int ch = b - HBLK0;
        if (ch < 0 || ch >= NCH) return;   // two-sided guard (R7 lesson)
        int e0 = ch * CHUNK;
        int e1 = e0 + CHUNK; if (e1 > EE) e1 = EE;
        for (int i = tid; i < NBKT; i += 256) hist[i] = 0;
        __syncthreads();
        for (int e = e0 + tid; e < e1; e += 256)
            atomicAdd(&hist[ei[EE + e] >> 9], 1);
        __syncthreads();
        for (int i = tid; i < NBKT; i += 256)
            chunkhist[i * NCH + ch] = hist[i];
    }
}

// ---------------- scan: bucket totals -> cbase; per-(bucket,chunk) scatter bases ----
__global__ void k_cscan(const int* __restrict__ chunkhist, int* __restrict__ cbase,
                        int* __restrict__ chunkbase) {
    __shared__ int s[256];
    int tid = threadIdx.x;
    int total = 0;
    if (tid < NBKT)
        for (int ch = 0; ch < NCH; ++ch) total += chunkhist[tid * NCH + ch];
    s[tid] = total;
    __syncthreads();
    for (int off = 1; off < 256; off <<= 1) {
        int t = (tid >= off) ? s[tid - off] : 0;
        __syncthreads();
        if (tid >= off) s[tid] += t;
        __syncthreads();
    }
    if (tid < NBKT) {
        int excl = s[tid] - total;
        cbase[tid] = excl;
        int run = excl;
        for (int ch = 0; ch < NCH; ++ch) {
            int t = chunkhist[tid * NCH + ch];
            chunkbase[tid * NCH + ch] = run;
            run += t;
        }
    }
    if (tid == NBKT - 1) cbase[NBKT] = s[tid];
}

// pairs packed: (src << 9) | (dst & 511)
// Single pass: per-chunk scatter bases precomputed by k_cscan (no hist pass,
// no gcur atomics).
__global__ __launch_bounds__(256)
void k_coarse(const int* __restrict__ ei, const int* __restrict__ chunkbase,
              int* __restrict__ pairs) {
    __shared__ int base[NBKT];
    __shared__ int curs[NBKT];
    int tid = threadIdx.x;
    int ch = blockIdx.x;
    int e0 = ch * CHUNK;
    int e1 = e0 + CHUNK; if (e1 > EE) e1 = EE;
    for (int i = tid; i < NBKT; i += 256) {
        base[i] = chunkbase[i * NCH + ch];
        curs[i] = 0;
    }
    __syncthreads();
    for (int e = e0 + tid; e < e1; e += 256) {
        int src = ei[e];
        int dst = ei[EE + e];
        int b = dst >> 9;
        int off = atomicAdd(&curs[b], 1);
        pairs[base[b] + off] = (src << 9) | (dst & 511);
    }
}

__global__ __launch_bounds__(512)
void k_fine(const int* __restrict__ cbase, const int* __restrict__ pairs,
            int* __restrict__ rs, int* __restrict__ esrc) {
    __shared__ int deg[BSZ];
    __shared__ int s[BSZ];
    int b = blockIdx.x;
    int n0 = b * BSZ;
    int nlocal = NN - n0; if (nlocal > BSZ) nlocal = BSZ;
    int tid = threadIdx.x;
    deg[tid] = 0;
    __syncthreads();
    int e0 = cbase[b], e1 = cbase[b + 1];
    for (int e = e0 + tid; e < e1; e += 512)
        atomicAdd(&deg[pairs[e] & 511], 1);
    __syncthreads();
    int v = deg[tid];
    s[tid] = v;
    __syncthreads();
    for (int off = 1; off < 512; off <<= 1) {
        int t = (tid >= off) ? s[tid - off] : 0;
        __syncthreads();
        if (tid >= off) s[tid] += t;
        __syncthreads();
    }
    int excl = s[tid] - v;
    if (tid < nlocal) rs[n0 + tid] = e0 + excl;
    if (b == NBKT - 1 && tid == 0) rs[NN] = EE;
    deg[tid] = e0 + excl;
    __syncthreads();
    for (int e = e0 + tid; e < e1; e += 512) {
        int pk = pairs[e];
        int pos = atomicAdd(&deg[pk & 511], 1);
        esrc[pos] = pk >> 9;
    }
}

// ---------------- aggregation (64-dim) over bf16 table -> bf16 mean ----------------
// R1 proven form (34.5us): 8 lanes/node, 4-edge unroll, 28 VGPR, high occupancy.
// R2 (fuse), R3 (unroll-8), R4 (shuffle-broadcast) all regressed — gather is
// concurrency-bound; this structure is the local optimum. DO NOT TOUCH the loop.
// BN scale/shift now computed in-prologue from bnacc (replaces k_bnfin launch).
__global__ __launch_bounds__(256, 8)
void k_aggbf(const unsigned short* __restrict__ xbf, const int* __restrict__ rs,
             const int* __restrict__ esrc, unsigned short* __restrict__ meanbf,
             const float* __restrict__ bnaccIn, const float* __restrict__ g,
             const float* __restrict__ be) {
    __shared__ float ls[128];
    const int tid = threadIdx.x;
    if (bnaccIn) BN_PROLOGUE(bnaccIn, g, be, ls);
    const int node = blockIdx.x * 32 + (tid >> 3);
    if (node >= NN) return;
    const int c = tid & 7;                 // feature octet
    const int s0 = rs[node], s1 = rs[node + 1];
    const uint4* xb = (const uint4*)xbf;
    f32x2 a0 = {0.f, 0.f}, a1 = a0, a2 = a0, a3 = a0;
    if (bnaccIn) {
        const f32x2* sc2 = (const f32x2*)ls;
        const f32x2* sh2 = (const f32x2*)(ls + 64);
        const f32x2 s0v = sc2[4 * c + 0], s1v = sc2[4 * c + 1];
        const f32x2 s2v = sc2[4 * c + 2], s3v = sc2[4 * c + 3];
        const f32x2 h0v = sh2[4 * c + 0], h1v = sh2[4 * c + 1];
        const f32x2 h2v = sh2[4 * c + 2], h3v = sh2[4 * c + 3];
        const f32x2 z = {0.f, 0.f};
#define ACCS(v) do { \
        a0 += __builtin_elementwise_max(__builtin_elementwise_fma(unpk2((v).x), s0v, h0v), z); \
        a1 += __builtin_elementwise_max(__builtin_elementwise_fma(unpk2((v).y), s1v, h1v), z); \
        a2 += __builtin_elementwise_max(__builtin_elementwise_fma(unpk2((v).z), s2v, h2v), z); \
        a3 += __builtin_elementwise_max(__builtin_elementwise_fma(unpk2((v).w), s3v, h3v), z); \
        } while (0)
        int p = s0;
        for (; p + 3 < s1; p += 4) {
            int e0 = esrc[p], e1 = esrc[p + 1], e2 = esrc[p + 2], e3 = esrc[p + 3];
            uint4 v0 = xb[(size_t)e0 * 8 + c];
            uint4 v1 = xb[(size_t)e1 * 8 + c];
            uint4 v2 = xb[(size_t)e2 * 8 + c];
            uint4 v3 = xb[(size_t)e3 * 8 + c];
            ACCS(v0); ACCS(v1); ACCS(v2); ACCS(v3);
        }
        for (; p < s1; ++p) {
            uint4 v = xb[(size_t)esrc[p] * 8 + c];
            ACCS(v);
        }
#undef ACCS
    } else {
#define ACCA(v) do { \
        a0 += unpk2((v).x); a1 += unpk2((v).y); \
        a2 += unpk2((v).z); a3 += unpk2((v).w); } while (0)
        int p = s0;
        for (; p + 3 < s1; p += 4) {
            int e0 = esrc[p], e1 = esrc[p + 1], e2 = esrc[p + 2], e3 = esrc[p + 3];
            uint4 v0 = xb[(size_t)e0 * 8 + c];
            uint4 v1 = xb[(size_t)e1 * 8 + c];
            uint4 v2 = xb[(size_t)e2 * 8 + c];
            uint4 v3 = xb[(size_t)e3 * 8 + c];
            ACCA(v0); ACCA(v1); ACCA(v2); ACCA(v3);
        }
        for (; p < s1; ++p) {
            uint4 v = xb[(size_t)esrc[p] * 8 + c];
            ACCA(v);
        }
#undef ACCA
    }
    int cnt = s1 - s0; if (cnt < 1) cnt = 1;
    float inv = 1.0f / (float)cnt;
    uint4 o;
    o.x = pack2(a0.x * inv, a0.y * inv);
    o.y = pack2(a1.x * inv, a1.y * inv);
    o.z = pack2(a2.x * inv, a2.y * inv);
    o.w = pack2(a3.x * inv, a3.y * inv);
    ((uint4*)meanbf)[(size_t)node * 8 + c] = o;
}

// ---------------- SAGE layer: LDS-free bf16 MFMA GEMM + bias + L2-norm + BN stats ----------------
// BN stats out: per-block LDS reduce, then one f32 atomicAdd per thread into an
// 8-way-spread global accumulator bnaccOut[8][128]. BN(in) scale/shift computed
// in-prologue from bnaccIn (replaces k_bnfin launch).
__global__ __launch_bounds__(256, 4)
void k_sagemfma(const unsigned short* __restrict__ meanbf,  // (N,64) bf16
                const unsigned short* __restrict__ a2bf,    // (N,64) bf16
                const unsigned short* __restrict__ Wbf,     // (64,128) bf16 packed
                const float* __restrict__ bias,
                unsigned short* __restrict__ outbf,         // (N,64) bf16
                float* __restrict__ bnaccOut,               // (8,128): sum|ssq
                const float* __restrict__ bnaccIn, const float* __restrict__ g,
                const float* __restrict__ be) {
    __shared__ float sblk[64];
    __shared__ float qblk[64];
    __shared__ float ls[128];
    const int tid = threadIdx.x;
    if (bnaccIn) BN_PROLOGUE(bnaccIn, g, be, ls);
    const int base = blockIdx.x * 64;
    const int col = tid & 15;
    const int q   = (tid >> 4) & 3;
    const int w   = tid >> 6;

    if (tid < 64) { sblk[tid] = 0.f; qblk[tid] = 0.f; }

    int gn = base + w * 16 + col; if (gn > NN - 1) gn = NN - 1;
    const uint4* mb = (const uint4*)meanbf;
    const uint4* ab = (const uint4*)a2bf;
    const uint4* wb = (const uint4*)Wbf;

    uint4 fa0 = mb[gn * 8 + q];
    uint4 fa1 = mb[gn * 8 + 4 + q];
    uint4 fa2 = ab[gn * 8 + q];
    uint4 fa3 = ab[gn * 8 + 4 + q];
    if (bnaccIn) {
        const float4* scp = (const float4*)ls;
        const float4* shp = (const float4*)(ls + 64);
        float4 s0 = scp[q * 2],     s1 = scp[q * 2 + 1];
        float4 h0 = shp[q * 2],     h1 = shp[q * 2 + 1];
        float4 s2 = scp[8 + q * 2], s3 = scp[8 + q * 2 + 1];
        float4 h2 = shp[8 + q * 2], h3 = shp[8 + q * 2 + 1];
        fa2.x = pack2(fmaxf(fmaf(bflo(fa2.x), s0.x, h0.x), 0.f),
                      fmaxf(fmaf(bfhi(fa2.x), s0.y, h0.y), 0.f));
        fa2.y = pack2(fmaxf(fmaf(bflo(fa2.y), s0.z, h0.z), 0.f),
                      fmaxf(fmaf(bfhi(fa2.y), s0.w, h0.w), 0.f));
        fa2.z = pack2(fmaxf(fmaf(bflo(fa2.z), s1.x, h1.x), 0.f),
                      fmaxf(fmaf(bfhi(fa2.z), s1.y, h1.y), 0.f));
        fa2.w = pack2(fmaxf(fmaf(bflo(fa2.w), s1.z, h1.z), 0.f),
                      fmaxf(fmaf(bfhi(fa2.w), s1.w, h1.w), 0.f));
        fa3.x = pack2(fmaxf(fmaf(bflo(fa3.x), s2.x, h2.x), 0.f),
                      fmaxf(fmaf(bfhi(fa3.x), s2.y, h2.y), 0.f));
        fa3.y = pack2(fmaxf(fmaf(bflo(fa3.y), s2.z, h2.z), 0.f),
                      fmaxf(fmaf(bfhi(fa3.y), s2.w, h2.w), 0.f));
        fa3.z = pack2(fmaxf(fmaf(bflo(fa3.z), s3.x, h3.x), 0.f),
                      fmaxf(fmaf(bfhi(fa3.z), s3.y, h3.y), 0.f));
        fa3.w = pack2(fmaxf(fmaf(bflo(fa3.w), s3.z, h3.z), 0.f),
                      fmaxf(fmaf(bfhi(fa3.w), s3.w, h3.w), 0.f));
    }
    uint4 fa[4] = {fa0, fa1, fa2, fa3};

    f32x4 acc0 = {0.f, 0.f, 0.f, 0.f}, acc1 = acc0, acc2 = acc0, acc3 = acc0;
#pragma unroll
    for (int c = 0; c < 4; ++c) {
        uint4 b0 = wb[(0 * 16 + col) * 16 + c * 4 + q];
        uint4 b1 = wb[(1 * 16 + col) * 16 + c * 4 + q];
        uint4 b2 = wb[(2 * 16 + col) * 16 + c * 4 + q];
        uint4 b3 = wb[(3 * 16 + col) * 16 + c * 4 + q];
        bf16x8 a = *(const bf16x8*)&fa[c];
        acc0 = __builtin_amdgcn_mfma_f32_16x16x32_bf16(a, *(const bf16x8*)&b0, acc0, 0, 0, 0);
        acc1 = __builtin_amdgcn_mfma_f32_16x16x32_bf16(a, *(const bf16x8*)&b1, acc1, 0, 0, 0);
        acc2 = __builtin_amdgcn_mfma_f32_16x16x32_bf16(a, *(const bf16x8*)&b2, acc2, 0, 0, 0);
        acc3 = __builtin_amdgcn_mfma_f32_16x16x32_bf16(a, *(const bf16x8*)&b3, acc3, 0, 0, 0);
    }

    float bb0 = bias[col], bb1 = bias[16 + col], bb2 = bias[32 + col], bb3 = bias[48 + col];
    float sj0 = 0.f, sj1 = 0.f, sj2 = 0.f, sj3 = 0.f;
    float qj0 = 0.f, qj1 = 0.f, qj2 = 0.f, qj3 = 0.f;
#pragma unroll
    for (int r = 0; r < 4; ++r) {
        int go = base + w * 16 + q * 4 + r;
        float o0 = acc0[r] + bb0, o1 = acc1[r] + bb1;
        float o2 = acc2[r] + bb2, o3 = acc3[r] + bb3;
        float ssv = o0 * o0 + o1 * o1 + o2 * o2 + o3 * o3;
        ssv += __shfl_xor(ssv, 1, 64);
        ssv += __shfl_xor(ssv, 2, 64);
        ssv += __shfl_xor(ssv, 4, 64);
        ssv += __shfl_xor(ssv, 8, 64);
        float inv = 1.0f / fmaxf(sqrtf(ssv), 1e-12f);
        o0 *= inv; o1 *= inv; o2 *= inv; o3 *= inv;
        if (go < NN) {
            outbf[go * 64 + col]      = bf16_of(o0);
            outbf[go * 64 + 16 + col] = bf16_of(o1);
            outbf[go * 64 + 32 + col] = bf16_of(o2);
            outbf[go * 64 + 48 + col] = bf16_of(o3);
            sj0 += o0; sj1 += o1; sj2 += o2; sj3 += o3;
            qj0 += o0 * o0; qj1 += o1 * o1; qj2 += o2 * o2; qj3 += o3 * o3;
        }
    }
#pragma unroll
    for (int m = 16; m <= 32; m <<= 1) {
        sj0 += __shfl_xor(sj0, m, 64); sj1 += __shfl_xor(sj1, m, 64);
        sj2 += __shfl_xor(sj2, m, 64); sj3 += __shfl_xor(sj3, m, 64);
        qj0 += __shfl_xor(qj0, m, 64); qj1 += __shfl_xor(qj1, m, 64);
        qj2 += __shfl_xor(qj2, m, 64); qj3 += __shfl_xor(qj3, m, 64);
    }
    __syncthreads();
    if (q == 0) {
        atomicAdd(&sblk[col], sj0);      atomicAdd(&qblk[col], qj0);
        atomicAdd(&sblk[16 + col], sj1); atomicAdd(&qblk[16 + col], qj1);
        atomicAdd(&sblk[32 + col], sj2); atomicAdd(&qblk[32 + col], qj2);
        atomicAdd(&sblk[48 + col], sj3); atomicAdd(&qblk[48 + col], qj3);
    }
    __syncthreads();
    if (tid < 128)
        atomicAdd(&bnaccOut[(blockIdx.x & 7) * 128 + tid],
                  (tid < 64) ? sblk[tid] : qblk[tid - 64]);
}

// ---------------- layer-3 projection (reads bf16 h2raw; BN2 from bnacc prologue) ----
__global__ __launch_bounds__(256)
void k_project(const unsigned short* __restrict__ h,     // h2 raw bf16 (N,64)
               const float* __restrict__ bnaccIn, const float* __restrict__ g,
               const float* __restrict__ be,
               const float* __restrict__ Wl, const float* __restrict__ Wr,
               const float* __restrict__ bias,
               float* __restrict__ zl, float* __restrict__ zr) {
    __shared__ float Alds[64 * 128];
    __shared__ float Wlds[64 * 32];
    __shared__ float ls[128];
    const int tid = threadIdx.x;
    const int base = blockIdx.x * 128;
    BN_PROLOGUE(bnaccIn, g, be, ls);

#pragma unroll
    for (int i = 0; i < 8; ++i) {
        int idx = i * 256 + tid;
        int f = idx & 31, k = idx >> 5;
        float v = 0.0f;
        if (f < 16) { if (f < 10) v = Wl[f * 64 + k]; }
        else        { if (f - 16 < 10) v = Wr[(f - 16) * 64 + k]; }
        Wlds[k * 32 + f] = v;
    }
    {
        const uint4* h4 = (const uint4*)h;
        const float4* sc4p = (const float4*)ls;
        const float4* sh4p = (const float4*)(ls + 64);
#pragma unroll
        for (int i = 0; i < 4; ++i) {
            int idx = i * 256 + tid;
            int node = idx & 127, cb = idx >> 7;
            int gn = base + node; if (gn > NN - 1) gn = NN - 1;
            uint4 u = h4[gn * 8 + cb];
            float4 sA = sc4p[cb * 2], sB = sc4p[cb * 2 + 1];
            float4 hA = sh4p[cb * 2], hB = sh4p[cb * 2 + 1];
            int k0 = cb * 8;
            Alds[(k0 + 0) * 128 + node] = fmaxf(fmaf(bflo(u.x), sA.x, hA.x), 0.f);
            Alds[(k0 + 1) * 128 + node] = fmaxf(fmaf(bfhi(u.x), sA.y, hA.y), 0.f);
            Alds[(k0 + 2) * 128 + node] = fmaxf(fmaf(bflo(u.y), sA.z, hA.z), 0.f);
            Alds[(k0 + 3) * 128 + node] = fmaxf(fmaf(bfhi(u.y), sA.w, hA.w), 0.f);
            Alds[(k0 + 4) * 128 + node] = fmaxf(fmaf(bflo(u.z), sB.x, hB.x), 0.f);
            Alds[(k0 + 5) * 128 + node] = fmaxf(fmaf(bfhi(u.z), sB.y, hB.y), 0.f);
            Alds[(k0 + 6) * 128 + node] = fmaxf(fmaf(bflo(u.w), sB.z, hB.z), 0.f);
            Alds[(k0 + 7) * 128 + node] = fmaxf(fmaf(bfhi(u.w), sB.w, hB.w), 0.f);
        }
    }
    __syncthreads();

    const int fg = tid & 7;
    const int ng = tid >> 3;

    float acc[4][4] = {};
#pragma unroll 4
    for (int k = 0; k < 64; ++k) {
        const float4 a = *(const float4*)(Alds + k * 128 + (ng << 2));
        const float4 w = *(const float4*)(Wlds + k * 32 + (fg << 2));
        const float av[4] = {a.x, a.y, a.z, a.w};
        const float wv[4] = {w.x, w.y, w.z, w.w};
#pragma unroll
        for (int i = 0; i < 4; ++i)
#pragma unroll
            for (int j = 0; j < 4; ++j)
                acc[i][j] = fmaf(av[i], wv[j], acc[i][j]);
    }

    if (fg == 3 || fg == 7) return;
    float4* dst = (fg < 4) ? (float4*)zl : (float4*)zr;
    int fq = (fg < 4) ? fg : fg - 4;
    float bx = 0.f, by = 0.f, bz = 0.f, bw = 0.f;
    if (fg >= 4) {
        int f0 = fq * 4;
        bx = (f0 + 0 < 10) ? bias[f0 + 0] : 0.f;
        by = (f0 + 1 < 10) ? bias[f0 + 1] : 0.f;
        bz = (f0 + 2 < 10) ? bias[f0 + 2] : 0.f;
        bw = (f0 + 3 < 10) ? bias[f0 + 3] : 0.f;
    }
#pragma unroll
    for (int i = 0; i < 4; ++i) {
        int gn = base + (ng << 2) + i;
        if (gn < NN)
            dst[gn * 3 + fq] = make_float4(acc[i][0] + bx, acc[i][1] + by,
                                           acc[i][2] + bz, acc[i][3] + bw);
    }
}

// ---------------- layer-3 aggregation (unroll-4 for MLP) ----------------
__global__ __launch_bounds__(256)
void k_agg10(const int* __restrict__ rs, const int* __restrict__ esrc,
             const float* __restrict__ zl, const float* __restrict__ zr,
             float* __restrict__ out) {
    int gid = blockIdx.x * 256 + threadIdx.x;
    unsigned node = (unsigned)gid / 3u;
    int j = gid - (int)node * 3;
    if (node >= NN) return;
    int s0 = rs[node], s1 = rs[node + 1];
    const float4* zl4 = (const float4*)zl;
    float4 acc = make_float4(0.f, 0.f, 0.f, 0.f);
    int p = s0;
    for (; p + 3 < s1; p += 4) {
        float4 v0 = zl4[esrc[p] * 3 + j];
        float4 v1 = zl4[esrc[p + 1] * 3 + j];
        float4 v2 = zl4[esrc[p + 2] * 3 + j];
        float4 v3 = zl4[esrc[p + 3] * 3 + j];
        acc.x += (v0.x + v1.x) + (v2.x + v3.x);
        acc.y += (v0.y + v1.y) + (v2.y + v3.y);
        acc.z += (v0.z + v1.z) + (v2.z + v3.z);
        acc.w += (v0.w + v1.w) + (v2.w + v3.w);
    }
    for (; p < s1; ++p) {
        float4 v = zl4[esrc[p] * 3 + j];
        acc.x += v.x; acc.y += v.y; acc.z += v.z; acc.w += v.w;
    }
    int cnt = s1 - s0; if (cnt < 1) cnt = 1;
    float inv = 1.0f / (float)cnt;
    float4 r = ((const float4*)zr)[node * 3 + j];
    r.x = fmaf(acc.x, inv, r.x); r.y = fmaf(acc.y, inv, r.y);
    r.z = fmaf(acc.z, inv, r.z); r.w = fmaf(acc.w, inv, r.w);
    float2* o2 = (float2*)(out + (size_t)node * 10);
    if (j < 2) {
        o2[j * 2 + 0] = make_float2(r.x, r.y);
        o2[j * 2 + 1] = make_float2(r.z, r.w);
    } else {
        o2[4] = make_float2(r.x, r.y);
    }
}

// ---------------- launch ----------------

extern "C" void kernel_launch(void* const* d_in, const int* in_sizes, int n_in,
                              void* d_out, int out_size, void* d_ws, size_t ws_size,
                              hipStream_t stream) {
    const float* x   = (const float*)d_in[0];
    const int*   ei  = (const int*)d_in[1];
    const float* Wl1 = (const float*)d_in[2];
    const float* Wr1 = (const float*)d_in[3];
    const float* b1  = (const float*)d_in[4];
    const float* g1  = (const float*)d_in[5];
    const float* be1 = (const float*)d_in[6];
    const float* Wl2 = (const float*)d_in[7];
    const float* Wr2 = (const float*)d_in[8];
    const float* b2  = (const float*)d_in[9];
    const float* g2  = (const float*)d_in[10];
    const float* be2 = (const float*)d_in[11];
    const float* Wl3 = (const float*)d_in[12];
    const float* Wr3 = (const float*)d_in[13];
    const float* b3  = (const float*)d_in[14];
    float* out = (float*)d_out;

    char* w = (char*)d_ws;
    auto alloc = [&](size_t bytes) -> void* {
        void* p = (void*)w;
        w += (bytes + 255) & ~(size_t)255;
        return p;
    };
    int*   cbase     = (int*)alloc(256 * 4);
    int*   chunkhist = (int*)alloc((size_t)NBKT * NCH * 4);
    int*   chunkbase = (int*)alloc((size_t)NBKT * NCH * 4);
    int*   rs     = (int*)alloc((size_t)(NN + 1) * 4);
    int*   esrc   = (int*)alloc((size_t)EE * 4);
    float* scratch= (float*)alloc((size_t)NN * 64 * 4);   // pairs / zl / zr
    unsigned short* xbf    = (unsigned short*)alloc((size_t)NN * 64 * 2);  // x bf16, then h2raw bf16
    unsigned short* h1bf   = (unsigned short*)alloc((size_t)NN * 64 * 2);
    unsigned short* meanbf = (unsigned short*)alloc((size_t)NN * 64 * 2);
    unsigned short* wbf1   = (unsigned short*)alloc(8192 * 2);
    unsigned short* wbf2   = (unsigned short*)alloc(8192 * 2);
    float* bnaccbuf = (float*)alloc(2048 * 4); // (2,8,128): layer1 | layer2 BN accum
    float* bnacc1 = bnaccbuf;
    float* bnacc2 = bnaccbuf + 1024;
    int*   pairs  = (int*)scratch;
    float* zl     = scratch;
    float* zr     = scratch + (size_t)NN * 12;

    // fused conversion (32B/thread) + W packing + per-chunk dst hists + bnacc zeroing
    k_tobfW<<<TOBFW_GRID, 256, 0, stream>>>((const float4*)x, (ushort4*)xbf,
                                            Wl1, Wr1, Wl2, Wr2, wbf1, wbf2,
                                            ei, chunkhist, bnaccbuf);
    k_cscan<<<1, 256, 0, stream>>>(chunkhist, cbase, chunkbase);
    k_coarse<<<NCH, 256, 0, stream>>>(ei, chunkbase, pairs);
    k_fine<<<NBKT, 512, 0, stream>>>(cbase, pairs, rs, esrc);

    const int aggBlocks  = (NN + 31) / 32;       // 3125 (32 nodes / block, 8 lanes each)
    const int sageBlocks = (NN + 63) / 64;       // 1563
    const int projBlocks = (NN + 127) / 128;     // 782
    const int a10Blocks  = (NN * 3 + 255) / 256; // 1172

    // layer 1: mean(xbf) -> meanbf; MFMA -> h1bf + bnacc1 stats
    k_aggbf<<<aggBlocks, 256, 0, stream>>>(xbf, rs, esrc, meanbf,
                                           nullptr, nullptr, nullptr);
    k_sagemfma<<<sageBlocks, 256, 0, stream>>>(meanbf, xbf, wbf1, b1, h1bf,
                                               bnacc1, nullptr, nullptr, nullptr);

    // layer 2: mean(relu(bn1(h1bf))) -> meanbf (BN1 from bnacc1 prologue);
    // MFMA (BN1 fused on A2) -> h2raw bf16 (reuses xbf) + bnacc2 stats
    k_aggbf<<<aggBlocks, 256, 0, stream>>>(h1bf, rs, esrc, meanbf,
                                           bnacc1, g1, be1);
    k_sagemfma<<<sageBlocks, 256, 0, stream>>>(meanbf, h1bf, wbf2, b2, xbf,
                                               bnacc2, bnacc1, g1, be1);

    // layer 3: project (BN2+ReLU from bnacc2 prologue, bf16 input) then 10-dim aggregate
    k_project<<<projBlocks, 256, 0, stream>>>(xbf, bnacc2, g2, be2,
                                              Wl3, Wr3, b3, zl, zr);
    k_agg10<<<a10Blocks, 256, 0, stream>>>(rs, esrc, zl, zr, out);
}

// Round 10
// 299.573 us; speedup vs baseline: 1.0195x; 1.0195x over previous
//
#include <hip/hip_runtime.h>
#include <hip/hip_bf16.h>

#define NN 100000
#define EE 1600000
#define BSZ 512    // dst-nodes per coarse bucket
#define NBKT 196   // ceil(NN/BSZ)
#define CHUNK 8192 // edges per coarse chunk
#define NCH 196    // ceil(EE/CHUNK)
#define FCAP 9216  // k_fine LDS pair capacity (P(bucket>FCAP) ~ 1e-15; guarded)

// k_tobfW role ranges — single source of truth for BOTH the in-kernel dispatch
// and the launch grid (R6/R7 crashes were ±1 errors here; proven in R8).
#define XBLK 3125              // x-convert blocks (512 float4 each)
#define HBLK0 (XBLK + 1)       // first histogram block (W-pack block is XBLK)
#define TOBFW_GRID (HBLK0 + NCH)

typedef short bf16x8 __attribute__((ext_vector_type(8)));
typedef float f32x4 __attribute__((ext_vector_type(4)));
typedef float f32x2 __attribute__((ext_vector_type(2)));

// ---------------- bf16 helpers ----------------
__device__ inline unsigned short bf16_of(float f) {
    __hip_bfloat16 h = __float2bfloat16(f);   // RNE
    return *reinterpret_cast<unsigned short*>(&h);
}
__device__ inline unsigned pack2(float a, float b) {
    return (unsigned)bf16_of(a) | ((unsigned)bf16_of(b) << 16);
}
__device__ inline float bflo(unsigned u) { return __uint_as_float(u << 16); }
__device__ inline float bfhi(unsigned u) { return __uint_as_float(u & 0xffff0000u); }
__device__ inline f32x2 unpk2(unsigned u) {
    f32x2 r; r.x = __uint_as_float(u << 16); r.y = __uint_as_float(u & 0xffff0000u);
    return r;
}

// BN finalize prologue (replaces k_bnfin): reduce bnacc[8][128] -> ls[0..63]=scale,
// ls[64..127]=shift. Same op order + division as the old k_bnfin -> identical
// values in every consumer block.
#define BN_PROLOGUE(bnaccp, gp, bep, lsbuf) do {                               \
    if (threadIdx.x < 128) {                                                   \
        float a_ = 0.f;                                                        \
        _Pragma("unroll")                                                      \
        for (int r_ = 0; r_ < 8; ++r_) a_ += (bnaccp)[r_ * 128 + threadIdx.x]; \
        (lsbuf)[threadIdx.x] = a_;                                             \
    }                                                                          \
    __syncthreads();                                                           \
    if (threadIdx.x < 64) {                                                    \
        float mu_ = (lsbuf)[threadIdx.x] / (float)NN;                          \
        float var_ = (lsbuf)[64 + threadIdx.x] / (float)NN - mu_ * mu_;        \
        var_ = fmaxf(var_, 0.0f);                                              \
        float sc_ = (gp)[threadIdx.x] / sqrtf(var_ + 1e-5f);                   \
        (lsbuf)[threadIdx.x] = sc_;                                            \
        (lsbuf)[64 + threadIdx.x] = (bep)[threadIdx.x] - mu_ * sc_;            \
    }                                                                          \
    __syncthreads();                                                           \
} while (0)

// ---------------- fused: x->bf16 (32B/thread) + W packing + per-chunk dst hists ----
__global__ __launch_bounds__(256)
void k_tobfW(const float4* __restrict__ src, ushort4* __restrict__ dst,
             const float* __restrict__ Wl1, const float* __restrict__ Wr1,
             const float* __restrict__ Wl2, const float* __restrict__ Wr2,
             unsigned short* __restrict__ w1, unsigned short* __restrict__ w2,
             const int* __restrict__ ei, int* __restrict__ chunkhist,
             float* __restrict__ bnacc) {
    int b = blockIdx.x, tid = threadIdx.x;
    if (b < XBLK) {
        int i = b * 512 + tid;
        float4 v0 = src[i];
        float4 v1 = src[i + 256];
        dst[i]       = make_ushort4(bf16_of(v0.x), bf16_of(v0.y), bf16_of(v0.z), bf16_of(v0.w));
        dst[i + 256] = make_ushort4(bf16_of(v1.x), bf16_of(v1.y), bf16_of(v1.z), bf16_of(v1.w));
    } else if (b == XBLK) {
        for (int i = tid; i < 8192; i += 256) {
            int n = i >> 7, k = i & 127;
            float v1 = (k < 64) ? Wl1[n * 64 + k] : Wr1[n * 64 + (k - 64)];
            w1[i] = bf16_of(v1);
            float v2 = (k < 64) ? Wl2[n * 64 + k] : Wr2[n * 64 + (k - 64)];
            w2[i] = bf16_of(v2);
        }
        for (int i = tid; i < 2048; i += 256) bnacc[i] = 0.f;
    } else {
        __shared__ int hist[NBKT];
        int ch = b - HBLK0;
        if (ch < 0 || ch >= NCH) return;   // two-sided guard (R7 lesson)
        int e0 = ch * CHUNK;
        int e1 = e0 + CHUNK; if (e1 > EE) e1 = EE;
        for (int i = tid; i < NBKT; i += 256) hist[i] = 0;
        __syncthreads();
        for (int e = e0 + tid; e < e1; e += 256)
            atomicAdd(&hist[ei[EE + e] >> 9], 1);
        __syncthreads();
        for (int i = tid; i < NBKT; i += 256)
            chunkhist[i * NCH + ch] = hist[i];
    }
}

// ---------------- scan: bucket totals -> cbase; per-(bucket,chunk) scatter bases ----
__global__ void k_cscan(const int* __restrict__ chunkhist, int* __restrict__ cbase,
                        int* __restrict__ chunkbase) {
    __shared__ int s[256];
    int tid = threadIdx.x;
    int total = 0;
    if (tid < NBKT)
        for (int ch = 0; ch < NCH; ++ch) total += chunkhist[tid * NCH + ch];
    s[tid] = total;
    __syncthreads();
    for (int off = 1; off < 256; off <<= 1) {
        int t = (tid >= off) ? s[tid - off] : 0;
        __syncthreads();
        if (tid >= off) s[tid] += t;
        __syncthreads();
    }
    if (tid < NBKT) {
        int excl = s[tid] - total;
        cbase[tid] = excl;
        int run = excl;
        for (int ch = 0; ch < NCH; ++ch) {
            int t = chunkhist[tid * NCH + ch];
            chunkbase[tid * NCH + ch] = run;
            run += t;
        }
    }
    if (tid == NBKT - 1) cbase[NBKT] = s[tid];
}

// pairs packed: (src << 9) | (dst & 511)
__global__ __launch_bounds__(256)
void k_coarse(const int* __restrict__ ei, const int* __restrict__ chunkbase,
              int* __restrict__ pairs) {
    __shared__ int base[NBKT];
    __shared__ int curs[NBKT];
    int tid = threadIdx.x;
    int ch = blockIdx.x;
    int e0 = ch * CHUNK;
    int e1 = e0 + CHUNK; if (e1 > EE) e1 = EE;
    for (int i = tid; i < NBKT; i += 256) {
        base[i] = chunkbase[i * NCH + ch];
        curs[i] = 0;
    }
    __syncthreads();
    for (int e = e0 + tid; e < e1; e += 256) {
        int src = ei[e];
        int dst = ei[EE + e];
        int b = dst >> 9;
        int off = atomicAdd(&curs[b], 1);
        pairs[base[b] + off] = (src << 9) | (dst & 511);
    }
}

// LDS-stages its bucket's pairs on the first pass so the scatter pass reads LDS
// instead of re-reading 6.4MB from global. FCAP overflow guarded (global fallback).
__global__ __launch_bounds__(512)
void k_fine(const int* __restrict__ cbase, const int* __restrict__ pairs,
            int* __restrict__ rs, int* __restrict__ esrc) {
    __shared__ int plds[FCAP];
    __shared__ int deg[BSZ];
    __shared__ int s[BSZ];
    int b = blockIdx.x;
    int n0 = b * BSZ;
    int nlocal = NN - n0; if (nlocal > BSZ) nlocal = BSZ;
    int tid = threadIdx.x;
    deg[tid] = 0;
    __syncthreads();
    int e0 = cbase[b], e1 = cbase[b + 1];
    for (int e = e0 + tid; e < e1; e += 512) {
        int pk = pairs[e];
        int li = e - e0;
        if (li < FCAP) plds[li] = pk;
        atomicAdd(&deg[pk & 511], 1);
    }
    __syncthreads();
    int v = deg[tid];
    s[tid] = v;
    __syncthreads();
    for (int off = 1; off < 512; off <<= 1) {
        int t = (tid >= off) ? s[tid - off] : 0;
        __syncthreads();
        if (tid >= off) s[tid] += t;
        __syncthreads();
    }
    int excl = s[tid] - v;
    if (tid < nlocal) rs[n0 + tid] = e0 + excl;
    if (b == NBKT - 1 && tid == 0) rs[NN] = EE;
    deg[tid] = e0 + excl;
    __syncthreads();
    for (int e = e0 + tid; e < e1; e += 512) {
        int li = e - e0;
        int pk = (li < FCAP) ? plds[li] : pairs[e];
        int pos = atomicAdd(&deg[pk & 511], 1);
        esrc[pos] = pk >> 9;
    }
}

// ---------------- aggregation (64-dim) over bf16 table -> bf16 mean ----------------
// R1 proven form (34.5us): 8 lanes/node, 4-edge unroll, 28 VGPR, high occupancy.
// R2 (fuse), R3 (unroll-8), R4 (shuffle-broadcast) all regressed — gather is
// concurrency-bound; this structure is the local optimum. DO NOT TOUCH the loop.
__global__ __launch_bounds__(256, 8)
void k_aggbf(const unsigned short* __restrict__ xbf, const int* __restrict__ rs,
             const int* __restrict__ esrc, unsigned short* __restrict__ meanbf,
             const float* __restrict__ bnaccIn, const float* __restrict__ g,
             const float* __restrict__ be) {
    __shared__ float ls[128];
    const int tid = threadIdx.x;
    if (bnaccIn) BN_PROLOGUE(bnaccIn, g, be, ls);
    const int node = blockIdx.x * 32 + (tid >> 3);
    if (node >= NN) return;
    const int c = tid & 7;                 // feature octet
    const int s0 = rs[node], s1 = rs[node + 1];
    const uint4* xb = (const uint4*)xbf;
    f32x2 a0 = {0.f, 0.f}, a1 = a0, a2 = a0, a3 = a0;
    if (bnaccIn) {
        const f32x2* sc2 = (const f32x2*)ls;
        const f32x2* sh2 = (const f32x2*)(ls + 64);
        const f32x2 s0v = sc2[4 * c + 0], s1v = sc2[4 * c + 1];
        const f32x2 s2v = sc2[4 * c + 2], s3v = sc2[4 * c + 3];
        const f32x2 h0v = sh2[4 * c + 0], h1v = sh2[4 * c + 1];
        const f32x2 h2v = sh2[4 * c + 2], h3v = sh2[4 * c + 3];
        const f32x2 z = {0.f, 0.f};
#define ACCS(v) do { \
        a0 += __builtin_elementwise_max(__builtin_elementwise_fma(unpk2((v).x), s0v, h0v), z); \
        a1 += __builtin_elementwise_max(__builtin_elementwise_fma(unpk2((v).y), s1v, h1v), z); \
        a2 += __builtin_elementwise_max(__builtin_elementwise_fma(unpk2((v).z), s2v, h2v), z); \
        a3 += __builtin_elementwise_max(__builtin_elementwise_fma(unpk2((v).w), s3v, h3v), z); \
        } while (0)
        int p = s0;
        for (; p + 3 < s1; p += 4) {
            int e0 = esrc[p], e1 = esrc[p + 1], e2 = esrc[p + 2], e3 = esrc[p + 3];
            uint4 v0 = xb[(size_t)e0 * 8 + c];
            uint4 v1 = xb[(size_t)e1 * 8 + c];
            uint4 v2 = xb[(size_t)e2 * 8 + c];
            uint4 v3 = xb[(size_t)e3 * 8 + c];
            ACCS(v0); ACCS(v1); ACCS(v2); ACCS(v3);
        }
        for (; p < s1; ++p) {
            uint4 v = xb[(size_t)esrc[p] * 8 + c];
            ACCS(v);
        }
#undef ACCS
    } else {
#define ACCA(v) do { \
        a0 += unpk2((v).x); a1 += unpk2((v).y); \
        a2 += unpk2((v).z); a3 += unpk2((v).w); } while (0)
        int p = s0;
        for (; p + 3 < s1; p += 4) {
            int e0 = esrc[p], e1 = esrc[p + 1], e2 = esrc[p + 2], e3 = esrc[p + 3];
            uint4 v0 = xb[(size_t)e0 * 8 + c];
            uint4 v1 = xb[(size_t)e1 * 8 + c];
            uint4 v2 = xb[(size_t)e2 * 8 + c];
            uint4 v3 = xb[(size_t)e3 * 8 + c];
            ACCA(v0); ACCA(v1); ACCA(v2); ACCA(v3);
        }
        for (; p < s1; ++p) {
            uint4 v = xb[(size_t)esrc[p] * 8 + c];
            ACCA(v);
        }
#undef ACCA
    }
    int cnt = s1 - s0; if (cnt < 1) cnt = 1;
    float inv = 1.0f / (float)cnt;
    uint4 o;
    o.x = pack2(a0.x * inv, a0.y * inv);
    o.y = pack2(a1.x * inv, a1.y * inv);
    o.z = pack2(a2.x * inv, a2.y * inv);
    o.w = pack2(a3.x * inv, a3.y * inv);
    ((uint4*)meanbf)[(size_t)node * 8 + c] = o;
}

// ---------------- SAGE layer: LDS-free bf16 MFMA GEMM + bias + L2-norm + BN stats ----------------
__global__ __launch_bounds__(256, 4)
void k_sagemfma(const unsigned short* __restrict__ meanbf,  // (N,64) bf16
                const unsigned short* __restrict__ a2bf,    // (N,64) bf16
                const unsigned short* __restrict__ Wbf,     // (64,128) bf16 packed
                const float* __restrict__ bias,
                unsigned short* __restrict__ outbf,         // (N,64) bf16
                float* __restrict__ bnaccOut,               // (8,128): sum|ssq
                const float* __restrict__ bnaccIn, const float* __restrict__ g,
                const float* __restrict__ be) {
    __shared__ float sblk[64];
    __shared__ float qblk[64];
    __shared__ float ls[128];
    const int tid = threadIdx.x;
    if (bnaccIn) BN_PROLOGUE(bnaccIn, g, be, ls);
    const int base = blockIdx.x * 64;
    const int col = tid & 15;
    const int q   = (tid >> 4) & 3;
    const int w   = tid >> 6;

    if (tid < 64) { sblk[tid] = 0.f; qblk[tid] = 0.f; }

    int gn = base + w * 16 + col; if (gn > NN - 1) gn = NN - 1;
    const uint4* mb = (const uint4*)meanbf;
    const uint4* ab = (const uint4*)a2bf;
    const uint4* wb = (const uint4*)Wbf;

    uint4 fa0 = mb[gn * 8 + q];
    uint4 fa1 = mb[gn * 8 + 4 + q];
    uint4 fa2 = ab[gn * 8 + q];
    uint4 fa3 = ab[gn * 8 + 4 + q];
    if (bnaccIn) {
        const float4* scp = (const float4*)ls;
        const float4* shp = (const float4*)(ls + 64);
        float4 s0 = scp[q * 2],     s1 = scp[q * 2 + 1];
        float4 h0 = shp[q * 2],     h1 = shp[q * 2 + 1];
        float4 s2 = scp[8 + q * 2], s3 = scp[8 + q * 2 + 1];
        float4 h2 = shp[8 + q * 2], h3 = shp[8 + q * 2 + 1];
        fa2.x = pack2(fmaxf(fmaf(bflo(fa2.x), s0.x, h0.x), 0.f),
                      fmaxf(fmaf(bfhi(fa2.x), s0.y, h0.y), 0.f));
        fa2.y = pack2(fmaxf(fmaf(bflo(fa2.y), s0.z, h0.z), 0.f),
                      fmaxf(fmaf(bfhi(fa2.y), s0.w, h0.w), 0.f));
        fa2.z = pack2(fmaxf(fmaf(bflo(fa2.z), s1.x, h1.x), 0.f),
                      fmaxf(fmaf(bfhi(fa2.z), s1.y, h1.y), 0.f));
        fa2.w = pack2(fmaxf(fmaf(bflo(fa2.w), s1.z, h1.z), 0.f),
                      fmaxf(fmaf(bfhi(fa2.w), s1.w, h1.w), 0.f));
        fa3.x = pack2(fmaxf(fmaf(bflo(fa3.x), s2.x, h2.x), 0.f),
                      fmaxf(fmaf(bfhi(fa3.x), s2.y, h2.y), 0.f));
        fa3.y = pack2(fmaxf(fmaf(bflo(fa3.y), s2.z, h2.z), 0.f),
                      fmaxf(fmaf(bfhi(fa3.y), s2.w, h2.w), 0.f));
        fa3.z = pack2(fmaxf(fmaf(bflo(fa3.z), s3.x, h3.x), 0.f),
                      fmaxf(fmaf(bfhi(fa3.z), s3.y, h3.y), 0.f));
        fa3.w = pack2(fmaxf(fmaf(bflo(fa3.w), s3.z, h3.z), 0.f),
                      fmaxf(fmaf(bfhi(fa3.w), s3.w, h3.w), 0.f));
    }
    uint4 fa[4] = {fa0, fa1, fa2, fa3};

    f32x4 acc0 = {0.f, 0.f, 0.f, 0.f}, acc1 = acc0, acc2 = acc0, acc3 = acc0;
#pragma unroll
    for (int c = 0; c < 4; ++c) {
        uint4 b0 = wb[(0 * 16 + col) * 16 + c * 4 + q];
        uint4 b1 = wb[(1 * 16 + col) * 16 + c * 4 + q];
        uint4 b2 = wb[(2 * 16 + col) * 16 + c * 4 + q];
        uint4 b3 = wb[(3 * 16 + col) * 16 + c * 4 + q];
        bf16x8 a = *(const bf16x8*)&fa[c];
        acc0 = __builtin_amdgcn_mfma_f32_16x16x32_bf16(a, *(const bf16x8*)&b0, acc0, 0, 0, 0);
        acc1 = __builtin_amdgcn_mfma_f32_16x16x32_bf16(a, *(const bf16x8*)&b1, acc1, 0, 0, 0);
        acc2 = __builtin_amdgcn_mfma_f32_16x16x32_bf16(a, *(const bf16x8*)&b2, acc2, 0, 0, 0);
        acc3 = __builtin_amdgcn_mfma_f32_16x16x32_bf16(a, *(const bf16x8*)&b3, acc3, 0, 0, 0);
    }

    float bb0 = bias[col], bb1 = bias[16 + col], bb2 = bias[32 + col], bb3 = bias[48 + col];
    float sj0 = 0.f, sj1 = 0.f, sj2 = 0.f, sj3 = 0.f;
    float qj0 = 0.f, qj1 = 0.f, qj2 = 0.f, qj3 = 0.f;
#pragma unroll
    for (int r = 0; r < 4; ++r) {
        int go = base + w * 16 + q * 4 + r;
        float o0 = acc0[r] + bb0, o1 = acc1[r] + bb1;
        float o2 = acc2[r] + bb2, o3 = acc3[r] + bb3;
        float ssv = o0 * o0 + o1 * o1 + o2 * o2 + o3 * o3;
        ssv += __shfl_xor(ssv, 1, 64);
        ssv += __shfl_xor(ssv, 2, 64);
        ssv += __shfl_xor(ssv, 4, 64);
        ssv += __shfl_xor(ssv, 8, 64);
        float inv = 1.0f / fmaxf(sqrtf(ssv), 1e-12f);
        o0 *= inv; o1 *= inv; o2 *= inv; o3 *= inv;
        if (go < NN) {
            outbf[go * 64 + col]      = bf16_of(o0);
            outbf[go * 64 + 16 + col] = bf16_of(o1);
            outbf[go * 64 + 32 + col] = bf16_of(o2);
            outbf[go * 64 + 48 + col] = bf16_of(o3);
            sj0 += o0; sj1 += o1; sj2 += o2; sj3 += o3;
            qj0 += o0 * o0; qj1 += o1 * o1; qj2 += o2 * o2; qj3 += o3 * o3;
        }
    }
#pragma unroll
    for (int m = 16; m <= 32; m <<= 1) {
        sj0 += __shfl_xor(sj0, m, 64); sj1 += __shfl_xor(sj1, m, 64);
        sj2 += __shfl_xor(sj2, m, 64); sj3 += __shfl_xor(sj3, m, 64);
        qj0 += __shfl_xor(qj0, m, 64); qj1 += __shfl_xor(qj1, m, 64);
        qj2 += __shfl_xor(qj2, m, 64); qj3 += __shfl_xor(qj3, m, 64);
    }
    __syncthreads();
    if (q == 0) {
        atomicAdd(&sblk[col], sj0);      atomicAdd(&qblk[col], qj0);
        atomicAdd(&sblk[16 + col], sj1); atomicAdd(&qblk[16 + col], qj1);
        atomicAdd(&sblk[32 + col], sj2); atomicAdd(&qblk[32 + col], qj2);
        atomicAdd(&sblk[48 + col], sj3); atomicAdd(&qblk[48 + col], qj3);
    }
    __syncthreads();
    if (tid < 128)
        atomicAdd(&bnaccOut[(blockIdx.x & 7) * 128 + tid],
                  (tid < 64) ? sblk[tid] : qblk[tid - 64]);
}

// ---------------- layer-3 projection (bf16 zl out; BN2 from bnacc prologue) ----
__global__ __launch_bounds__(256)
void k_project(const unsigned short* __restrict__ h,     // h2 raw bf16 (N,64)
               const float* __restrict__ bnaccIn, const float* __restrict__ g,
               const float* __restrict__ be,
               const float* __restrict__ Wl, const float* __restrict__ Wr,
               const float* __restrict__ bias,
               unsigned short* __restrict__ zl,           // (N,12) bf16
               float* __restrict__ zr) {                  // (N,12) f32
    __shared__ float Alds[64 * 128];
    __shared__ float Wlds[64 * 32];
    __shared__ float ls[128];
    const int tid = threadIdx.x;
    const int base = blockIdx.x * 128;
    BN_PROLOGUE(bnaccIn, g, be, ls);

#pragma unroll
    for (int i = 0; i < 8; ++i) {
        int idx = i * 256 + tid;
        int f = idx & 31, k = idx >> 5;
        float v = 0.0f;
        if (f < 16) { if (f < 10) v = Wl[f * 64 + k]; }
        else        { if (f - 16 < 10) v = Wr[(f - 16) * 64 + k]; }
        Wlds[k * 32 + f] = v;
    }
    {
        const uint4* h4 = (const uint4*)h;
        const float4* sc4p = (const float4*)ls;
        const float4* sh4p = (const float4*)(ls + 64);
#pragma unroll
        for (int i = 0; i < 4; ++i) {
            int idx = i * 256 + tid;
            int node = idx & 127, cb = idx >> 7;
            int gn = base + node; if (gn > NN - 1) gn = NN - 1;
            uint4 u = h4[gn * 8 + cb];
            float4 sA = sc4p[cb * 2], sB = sc4p[cb * 2 + 1];
            float4 hA = sh4p[cb * 2], hB = sh4p[cb * 2 + 1];
            int k0 = cb * 8;
            Alds[(k0 + 0) * 128 + node] = fmaxf(fmaf(bflo(u.x), sA.x, hA.x), 0.f);
            Alds[(k0 + 1) * 128 + node] = fmaxf(fmaf(bfhi(u.x), sA.y, hA.y), 0.f);
            Alds[(k0 + 2) * 128 + node] = fmaxf(fmaf(bflo(u.y), sA.z, hA.z), 0.f);
            Alds[(k0 + 3) * 128 + node] = fmaxf(fmaf(bfhi(u.y), sA.w, hA.w), 0.f);
            Alds[(k0 + 4) * 128 + node] = fmaxf(fmaf(bflo(u.z), sB.x, hB.x), 0.f);
            Alds[(k0 + 5) * 128 + node] = fmaxf(fmaf(bfhi(u.z), sB.y, hB.y), 0.f);
            Alds[(k0 + 6) * 128 + node] = fmaxf(fmaf(bflo(u.w), sB.z, hB.z), 0.f);
            Alds[(k0 + 7) * 128 + node] = fmaxf(fmaf(bfhi(u.w), sB.w, hB.w), 0.f);
        }
    }
    __syncthreads();

    const int fg = tid & 7;
    const int ng = tid >> 3;

    float acc[4][4] = {};
#pragma unroll 4
    for (int k = 0; k < 64; ++k) {
        const float4 a = *(const float4*)(Alds + k * 128 + (ng << 2));
        const float4 w = *(const float4*)(Wlds + k * 32 + (fg << 2));
        const float av[4] = {a.x, a.y, a.z, a.w};
        const float wv[4] = {w.x, w.y, w.z, w.w};
#pragma unroll
        for (int i = 0; i < 4; ++i)
#pragma unroll
            for (int j = 0; j < 4; ++j)
                acc[i][j] = fmaf(av[i], wv[j], acc[i][j]);
    }

    if (fg == 3 || fg == 7) return;
    if (fg < 4) {
        // zl: bf16 (N,12) — halves the random-gather bytes in k_agg10
        int fq = fg;
#pragma unroll
        for (int i = 0; i < 4; ++i) {
            int gn = base + (ng << 2) + i;
            if (gn < NN) {
                uint2 o;
                o.x = pack2(acc[i][0], acc[i][1]);
                o.y = pack2(acc[i][2], acc[i][3]);
                ((uint2*)zl)[gn * 3 + fq] = o;
            }
        }
    } else {
        // zr: f32 + bias (bias stays full precision on the self path)
        int fq = fg - 4;
        int f0 = fq * 4;
        float bx = (f0 + 0 < 10) ? bias[f0 + 0] : 0.f;
        float by = (f0 + 1 < 10) ? bias[f0 + 1] : 0.f;
        float bz = (f0 + 2 < 10) ? bias[f0 + 2] : 0.f;
        float bw = (f0 + 3 < 10) ? bias[f0 + 3] : 0.f;
#pragma unroll
        for (int i = 0; i < 4; ++i) {
            int gn = base + (ng << 2) + i;
            if (gn < NN)
                ((float4*)zr)[gn * 3 + fq] = make_float4(acc[i][0] + bx, acc[i][1] + by,
                                                         acc[i][2] + bz, acc[i][3] + bw);
        }
    }
}

// ---------------- layer-3 aggregation (bf16 zl gather, 8B/edge/thread) ----------------
__global__ __launch_bounds__(256)
void k_agg10(const int* __restrict__ rs, const int* __restrict__ esrc,
             const unsigned short* __restrict__ zl, const float* __restrict__ zr,
             float* __restrict__ out) {
    int gid = blockIdx.x * 256 + threadIdx.x;
    unsigned node = (unsigned)gid / 3u;
    int j = gid - (int)node * 3;
    if (node >= NN) return;
    int s0 = rs[node], s1 = rs[node + 1];
    const uint2* zl2 = (const uint2*)zl;
    float4 acc = make_float4(0.f, 0.f, 0.f, 0.f);
    int p = s0;
    for (; p + 3 < s1; p += 4) {
        uint2 u0 = zl2[esrc[p] * 3 + j];
        uint2 u1 = zl2[esrc[p + 1] * 3 + j];
        uint2 u2 = zl2[esrc[p + 2] * 3 + j];
        uint2 u3 = zl2[esrc[p + 3] * 3 + j];
        acc.x += (bflo(u0.x) + bflo(u1.x)) + (bflo(u2.x) + bflo(u3.x));
        acc.y += (bfhi(u0.x) + bfhi(u1.x)) + (bfhi(u2.x) + bfhi(u3.x));
        acc.z += (bflo(u0.y) + bflo(u1.y)) + (bflo(u2.y) + bflo(u3.y));
        acc.w += (bfhi(u0.y) + bfhi(u1.y)) + (bfhi(u2.y) + bfhi(u3.y));
    }
    for (; p < s1; ++p) {
        uint2 u = zl2[esrc[p] * 3 + j];
        acc.x += bflo(u.x); acc.y += bfhi(u.x);
        acc.z += bflo(u.y); acc.w += bfhi(u.y);
    }
    int cnt = s1 - s0; if (cnt < 1) cnt = 1;
    float inv = 1.0f / (float)cnt;
    float4 r = ((const float4*)zr)[node * 3 + j];
    r.x = fmaf(acc.x, inv, r.x); r.y = fmaf(acc.y, inv, r.y);
    r.z = fmaf(acc.z, inv, r.z); r.w = fmaf(acc.w, inv, r.w);
    float2* o2 = (float2*)(out + (size_t)node * 10);
    if (j < 2) {
        o2[j * 2 + 0] = make_float2(r.x, r.y);
        o2[j * 2 + 1] = make_float2(r.z, r.w);
    } else {
        o2[4] = make_float2(r.x, r.y);
    }
}

// ---------------- launch ----------------

extern "C" void kernel_launch(void* const* d_in, const int* in_sizes, int n_in,
                              void* d_out, int out_size, void* d_ws, size_t ws_size,
                              hipStream_t stream) {
    const float* x   = (const float*)d_in[0];
    const int*   ei  = (const int*)d_in[1];
    const float* Wl1 = (const float*)d_in[2];
    const float* Wr1 = (const float*)d_in[3];
    const float* b1  = (const float*)d_in[4];
    const float* g1  = (const float*)d_in[5];
    const float* be1 = (const float*)d_in[6];
    const float* Wl2 = (const float*)d_in[7];
    const float* Wr2 = (const float*)d_in[8];
    const float* b2  = (const float*)d_in[9];
    const float* g2  = (const float*)d_in[10];
    const float* be2 = (const float*)d_in[11];
    const float* Wl3 = (const float*)d_in[12];
    const float* Wr3 = (const float*)d_in[13];
    const float* b3  = (const float*)d_in[14];
    float* out = (float*)d_out;

    char* w = (char*)d_ws;
    auto alloc = [&](size_t bytes) -> void* {
        void* p = (void*)w;
        w += (bytes + 255) & ~(size_t)255;
        return p;
    };
    int*   cbase     = (int*)alloc(256 * 4);
    int*   chunkhist = (int*)alloc((size_t)NBKT * NCH * 4);
    int*   chunkbase = (int*)alloc((size_t)NBKT * NCH * 4);
    int*   rs     = (int*)alloc((size_t)(NN + 1) * 4);
    int*   esrc   = (int*)alloc((size_t)EE * 4);
    float* scratch= (float*)alloc((size_t)NN * 64 * 4);   // pairs / zr+zl
    unsigned short* xbf    = (unsigned short*)alloc((size_t)NN * 64 * 2);  // x bf16, then h2raw bf16
    unsigned short* h1bf   = (unsigned short*)alloc((size_t)NN * 64 * 2);
    unsigned short* meanbf = (unsigned short*)alloc((size_t)NN * 64 * 2);
    unsigned short* wbf1   = (unsigned short*)alloc(8192 * 2);
    unsigned short* wbf2   = (unsigned short*)alloc(8192 * 2);
    float* bnaccbuf = (float*)alloc(2048 * 4); // (2,8,128): layer1 | layer2 BN accum
    float* bnacc1 = bnaccbuf;
    float* bnacc2 = bnaccbuf + 1024;
    int*   pairs  = (int*)scratch;                         // dead after k_fine
    float* zr     = scratch;                               // (N,12) f32 = 4.8MB
    unsigned short* zlbf = (unsigned short*)(scratch + (size_t)NN * 12); // (N,12) bf16

    // fused conversion (32B/thread) + W packing + per-chunk dst hists + bnacc zeroing
    k_tobfW<<<TOBFW_GRID, 256, 0, stream>>>((const float4*)x, (ushort4*)xbf,
                                            Wl1, Wr1, Wl2, Wr2, wbf1, wbf2,
                                            ei, chunkhist, bnaccbuf);
    k_cscan<<<1, 256, 0, stream>>>(chunkhist, cbase, chunkbase);
    k_coarse<<<NCH, 256, 0, stream>>>(ei, chunkbase, pairs);
    k_fine<<<NBKT, 512, 0, stream>>>(cbase, pairs, rs, esrc);

    const int aggBlocks  = (NN + 31) / 32;       // 3125 (32 nodes / block, 8 lanes each)
    const int sageBlocks = (NN + 63) / 64;       // 1563
    const int projBlocks = (NN + 127) / 128;     // 782
    const int a10Blocks  = (NN * 3 + 255) / 256; // 1172

    // layer 1: mean(xbf) -> meanbf; MFMA -> h1bf + bnacc1 stats
    k_aggbf<<<aggBlocks, 256, 0, stream>>>(xbf, rs, esrc, meanbf,
                                           nullptr, nullptr, nullptr);
    k_sagemfma<<<sageBlocks, 256, 0, stream>>>(meanbf, xbf, wbf1, b1, h1bf,
                                               bnacc1, nullptr, nullptr, nullptr);

    // layer 2: mean(relu(bn1(h1bf))) -> meanbf (BN1 from bnacc1 prologue);
    // MFMA (BN1 fused on A2) -> h2raw bf16 (reuses xbf) + bnacc2 stats
    k_aggbf<<<aggBlocks, 256, 0, stream>>>(h1bf, rs, esrc, meanbf,
                                           bnacc1, g1, be1);
    k_sagemfma<<<sageBlocks, 256, 0, stream>>>(meanbf, h1bf, wbf2, b2, xbf,
                                               bnacc2, bnacc1, g1, be1);

    // layer 3: project (BN2+ReLU from bnacc2 prologue, bf16 zl out) then 10-dim aggregate
    k_project<<<projBlocks, 256, 0, stream>>>(xbf, bnacc2, g2, be2,
                                              Wl3, Wr3, b3, zlbf, zr);
    k_agg10<<<a10Blocks, 256, 0, stream>>>(rs, esrc, zlbf, zr, out);
}